// Round 8
// baseline (241.662 us; speedup 1.0000x reference)
//
#include <hip/hip_runtime.h>
#include <hip/hip_bf16.h>
#include <stdint.h>

typedef __attribute__((ext_vector_type(8))) short bf16x8;
typedef __attribute__((ext_vector_type(4))) float f32x4;
typedef __attribute__((address_space(1))) const void g_void;
typedef __attribute__((address_space(3))) void l_void;

#define NB 16
#define NC 256
#define NHW 4096
#define NT 72      // K-steps: 9 taps x 8 ci-blocks
#define NSLOT 8192 // N-operand tile: 128 rows x 32 k x 2B

// ---------- prep: x NCHW f32 -> xt2 [b][cib][4096 pix][32 ci] bf16 ----------
__global__ __launch_bounds__(256) void prep_xt2(const float* __restrict__ x,
                                                __hip_bfloat16* __restrict__ xt2) {
  __shared__ float tile[64][65];
  const int b = blockIdx.z;
  const int cb = blockIdx.y << 6;
  const int pb = blockIdx.x << 6;
  const float* xs = x + ((size_t)(b * NC + cb) << 12) + pb;
#pragma unroll
  for (int k = 0; k < 16; ++k) {
    int idx = threadIdx.x + (k << 8);
    int c = idx >> 6, p = idx & 63;
    tile[p][c] = xs[((size_t)c << 12) + p];
  }
  __syncthreads();
#pragma unroll
  for (int k = 0; k < 16; ++k) {
    int idx = threadIdx.x + (k << 8);
    int p = idx >> 6, c = idx & 63;
    int P = pb + p, C = cb + c;
    xt2[((size_t)(b * 8 + (C >> 5)) << 17) + ((size_t)P << 5) + (C & 31)] =
        __float2bfloat16(tile[p][c]);
  }
}

// ---------- prep: kernel [b][co][ci][3][3] f32 -> kt2 [b][ct][tn][128][32] bf16 ----
// tn = cib*9+s; chunk pre-swizzled: stored-slot = chunk ^ ((row>>1)&3)
__global__ __launch_bounds__(256) void prep_kt2(const float* __restrict__ kin,
                                                __hip_bfloat16* __restrict__ kt2) {
  const int bco = blockIdx.x;  // b*256 + co
  const int b = bco >> 8, co = bco & 255;
  const size_t base = (size_t)bco * 2304;
  const int ci = threadIdx.x;
  float v[9];
#pragma unroll
  for (int s = 0; s < 9; ++s) v[s] = kin[base + ci * 9 + s];
  const int cib = ci >> 5, chunk = (ci >> 3) & 3, e = ci & 7;
  const int row = co & 127, ct = co >> 7;
  const int sc = chunk ^ ((row >> 1) & 3);
#pragma unroll
  for (int s = 0; s < 9; ++s) {
    const size_t dst = (((size_t)(b * 2 + ct) * NT + (cib * 9 + s)) << 12) +
                       (row << 5) + (sc << 3) + e;
    kt2[dst] = __float2bfloat16(v[s]);
  }
}

__global__ void zero_zp(float* zp) { zp[blockIdx.x * 256 + threadIdx.x] = 0.f; }

// ---------- implicit-GEMM conv, 128x128 tile, 4 blocks/CU, M-direct + N-LDS ----
// PASS 1: M=image(pixel) direct, N=kernel LDS; out = ht2 bf16 (relu)
// PASS 2: M=kernel(co) direct, N=image LDS; out = fp32 NCHW (x + .., relu)
template <int PASS>
__global__ __launch_bounds__(256, 4) void conv_gemm(
    const __hip_bfloat16* __restrict__ img2,  // [B][8][4096][32] (xt2 or ht2)
    const __hip_bfloat16* __restrict__ kt2,   // [B][2][72][128][32] pre-swizzled
    const float* __restrict__ xres,           // pass2 residual (NCHW f32)
    const __hip_bfloat16* __restrict__ zp,    // 8KB zeros
    void* __restrict__ outp) {
  __shared__ __align__(16) char L[3 * NSLOT];  // 24KB: N-operand, 3-slot pipeline

  const int tid = threadIdx.x;
  const int lane = tid & 63;
  const int wid = tid >> 6;  // 0..3 = M-subrow (32 rows each)

  // XCD-affine: XCD x owns logical 128-block chunk = 2 complete samples
  const int orig = blockIdx.x;
  const int g = ((orig & 7) << 7) + (orig >> 3);
  const int b = g >> 6;
  const int t = g & 63;
  const int ptile = t >> 1;
  const int ct = t & 1;
  const int pbase = ptile << 7;

  const char* xb = (const char*)img2 + ((size_t)b << 21);
  const char* ktb = (const char*)kt2 + (((size_t)(b * 2 + ct) * NT) << 13);
  const char* zpb = (const char*)zp;

  // N-LDS staging lane geometry (pre-swizzled source chunk)
  const int srow = lane >> 2;
  const int sch = (lane & 3) ^ ((srow >> 1) & 3);

  // M-direct addressing
  const int chk = (lane >> 4) << 4;  // k-chunk byte offset
  int pm[2], krowoff[2];
#pragma unroll
  for (int f = 0; f < 2; ++f) {
    const int rM = (wid << 5) + (f << 4) + (lane & 15);
    pm[f] = pbase + rM;                                           // pass1: pixel row
    krowoff[f] = (rM << 6) + (((lane >> 4) ^ ((rM >> 1) & 3)) << 4);  // pass2: kt2 row
  }
  // N-LDS fragment read offsets (swizzled)
  int boff[8];
#pragma unroll
  for (int j = 0; j < 8; ++j) {
    const int cj = (j << 4) + (lane & 15);
    boff[j] = (cj << 6) + (((lane >> 4) ^ ((cj >> 1) & 3)) << 4);
  }
  // image-edge kill masks
  const bool killAlo = ((wid & 1) == 0) && ((lane & 15) == 0);   // pass1 M-frag 0
  const bool killAhi = ((wid & 1) == 1) && ((lane & 15) == 15);  // pass1 M-frag 1
  const bool killlo = (lane & 15) == 0;                          // pass2 N-frag j%4==0
  const bool killhi = (lane & 15) == 15;                         // pass2 N-frag j%4==3
  const bf16x8 z8 = {0, 0, 0, 0, 0, 0, 0, 0};

  f32x4 acc[2][8];
#pragma unroll
  for (int i = 0; i < 2; ++i)
#pragma unroll
    for (int j = 0; j < 8; ++j) acc[i][j] = (f32x4){0.f, 0.f, 0.f, 0.f};

  auto stageN = [&](int tn, int slot, int s2) {
    char* dstb = L + slot * NSLOT;
    if (PASS == 1) {  // kernel tile: contiguous 8KB, pre-swizzled in memory
      const char* src0 = ktb + ((size_t)tn << 13);
#pragma unroll
      for (int i = 0; i < 2; ++i) {
        const int grp = (i << 2) + wid;
        const char* src = (tn < NT) ? src0 + (grp << 10) + (lane << 4) : zpb + (lane << 4);
        __builtin_amdgcn_global_load_lds((g_void*)src, (l_void*)(dstb + (grp << 10)), 16, 0, 0);
      }
    } else {  // image tile: contiguous 8KB at tap offset, swizzle via source
      const int dh = s2 / 3 - 1, dw = s2 % 3 - 1;
      const char* cb = xb + ((size_t)((tn / 9) & 7) << 18);
      const bool dummy = tn >= NT;
#pragma unroll
      for (int i = 0; i < 2; ++i) {
        const int grp = (i << 2) + wid;
        const int h = (ptile << 1) + (grp >> 2) + dh;  // uniform per instr
        const bool ok = !dummy && ((unsigned)h < 64u);
        const int off = ((pbase + (grp << 4) + srow + (dh << 6) + dw) << 6) + (sch << 4);
        const char* src = ok ? cb + off : zpb + (lane << 4);
        __builtin_amdgcn_global_load_lds((g_void*)src, (l_void*)(dstb + (grp << 10)), 16, 0, 0);
      }
    }
  };

  auto loadM = [&](int tn, int s, bf16x8* dst) {
    if (PASS == 1) {  // image rows, per-lane exact OOB -> zp; w-wrap killed at use
      const int tap = (s / 3 - 1) * 64 + (s % 3 - 1);
      const char* cb = xb + ((size_t)((tn / 9) & 7) << 18);
#pragma unroll
      for (int f = 0; f < 2; ++f) {
        const int pr = pm[f] + tap;
        const bool ok = (tn < NT) && ((unsigned)pr < 4096u);
        const char* src = ok ? cb + ((size_t)pr << 6) + chk : zpb + chk;
        dst[f] = *(const bf16x8*)src;
      }
    } else {  // kernel rows (un-swizzle stored chunk)
      const char* kb = ktb + ((size_t)tn << 13);
#pragma unroll
      for (int f = 0; f < 2; ++f) {
        const char* src = (tn < NT) ? kb + krowoff[f] : zpb + chk;
        dst[f] = *(const bf16x8*)src;
      }
    }
  };

  // prologue: N(0)->slot0, N(1)->slot1, M(0)->m0   [6 VM ops in flight]
  stageN(0, 0, 0);
  stageN(1, 1, 1);
  bf16x8 m0[2], m1[2];
  loadM(0, 0, m0);

#pragma unroll 1
  for (int t18 = 0; t18 < 4; ++t18) {
    const int base = t18 * 18;
#pragma unroll
    for (int u = 0; u < 18; ++u) {  // u, s, slot, parity all compile-time
      const int kk = base + u;
      const int s = u % 9;
      // N(kk) staged 2 steps ago -> guaranteed drained by vmcnt(2); M(kk) reg
      // loads get compiler-inserted counted waits before first use.
      asm volatile("s_waitcnt vmcnt(2)" ::: "memory");
      __builtin_amdgcn_s_barrier();
      stageN(kk + 2, (u + 2) % 3, (u + 2) % 9);
      bf16x8* cur = (u & 1) ? m1 : m0;
      bf16x8* nxt = (u & 1) ? m0 : m1;
      loadM(kk + 1, (u + 1) % 9, nxt);

      const char* Ns = L + (u % 3) * NSLOT;
      const int dw = s % 3 - 1;
      bf16x8 a0 = cur[0], a1 = cur[1];
      if (PASS == 1) {
        if (dw == -1) a0 = killAlo ? z8 : a0;
        if (dw == 1) a1 = killAhi ? z8 : a1;
      }
#pragma unroll
      for (int half = 0; half < 2; ++half) {
        bf16x8 fb[4];
#pragma unroll
        for (int j = 0; j < 4; ++j) fb[j] = *(const bf16x8*)(Ns + boff[(half << 2) + j]);
        if (PASS == 2) {
          if (dw == -1) fb[0] = killlo ? z8 : fb[0];
          if (dw == 1) fb[3] = killhi ? z8 : fb[3];
        }
        __builtin_amdgcn_s_setprio(1);
#pragma unroll
        for (int j = 0; j < 4; ++j) {
          acc[0][(half << 2) + j] =
              __builtin_amdgcn_mfma_f32_16x16x32_bf16(a0, fb[j], acc[0][(half << 2) + j], 0, 0, 0);
          acc[1][(half << 2) + j] =
              __builtin_amdgcn_mfma_f32_16x16x32_bf16(a1, fb[j], acc[1][(half << 2) + j], 0, 0, 0);
        }
        __builtin_amdgcn_s_setprio(0);
      }
    }
  }
  // drain tail dummy LDS-DMA before epilogue/endpgm
  asm volatile("s_waitcnt vmcnt(0)" ::: "memory");
  __builtin_amdgcn_sched_barrier(0);

  const int lg = lane >> 4;
  const int ln = lane & 15;
  if (PASS == 1) {
    __hip_bfloat16* ho = (__hip_bfloat16*)outp;  // ht2 [b][cib][pix][32]
#pragma unroll
    for (int i = 0; i < 2; ++i)
#pragma unroll
      for (int j = 0; j < 8; ++j)
#pragma unroll
        for (int r = 0; r < 4; ++r) {
          int pixel = pbase + (wid << 5) + (i << 4) + (lg << 2) + r;
          int co = (ct << 7) + (j << 4) + ln;
          float v = acc[i][j][r];
          v = v > 0.f ? v : 0.f;
          ho[((size_t)(b * 8 + (co >> 5)) << 17) + ((size_t)pixel << 5) + (co & 31)] =
              __float2bfloat16(v);
        }
  } else {
    float* oo = (float*)outp;
#pragma unroll
    for (int i = 0; i < 2; ++i)
#pragma unroll
      for (int j = 0; j < 8; ++j)
#pragma unroll
        for (int r = 0; r < 4; ++r) {
          int co = (ct << 7) + (wid << 5) + (i << 4) + (lg << 2) + r;
          int pixel = pbase + (j << 4) + ln;
          size_t idx = ((size_t)(b * NC + co) << 12) + pixel;
          float v = acc[i][j][r] + xres[idx];
          oo[idx] = v > 0.f ? v : 0.f;
        }
  }
}

extern "C" void kernel_launch(void* const* d_in, const int* in_sizes, int n_in,
                              void* d_out, int out_size, void* d_ws, size_t ws_size,
                              hipStream_t stream) {
  const float* x = (const float*)d_in[0];
  const float* k1 = (const float*)d_in[1];
  const float* k2 = (const float*)d_in[2];

  // ws: pad 256B | xt2 (33.6MB) | ht2 (33.6MB) | kt2 (18.9MB) | zp (8KB)
  char* w = (char*)d_ws;
  __hip_bfloat16* xt2 = (__hip_bfloat16*)(w + 256);
  __hip_bfloat16* ht2 = xt2 + (size_t)NB * 8 * NHW * 32;
  __hip_bfloat16* kt2 = ht2 + (size_t)NB * 8 * NHW * 32;
  float* zp = (float*)(kt2 + (size_t)NB * 2 * NT * 128 * 32);

  zero_zp<<<dim3(8), 256, 0, stream>>>(zp);
  prep_xt2<<<dim3(64, 4, NB), 256, 0, stream>>>(x, xt2);
  prep_kt2<<<dim3(NB * NC), 256, 0, stream>>>(k1, kt2);
  conv_gemm<1><<<dim3(1024), 256, 0, stream>>>(xt2, kt2, nullptr,
                                               (const __hip_bfloat16*)zp, (void*)ht2);
  prep_kt2<<<dim3(NB * NC), 256, 0, stream>>>(k2, kt2);
  conv_gemm<2><<<dim3(1024), 256, 0, stream>>>(ht2, kt2, x,
                                               (const __hip_bfloat16*)zp, d_out);
}